// Round 5
// baseline (82.936 us; speedup 1.0000x reference)
//
#include <hip/hip_runtime.h>
#include <hip/hip_bf16.h>

#define N_NODES 50000
#define HID     256
#define N_EDGES 300000
#define NT      32   // nodes per GEMM tile
#define NTILES  ((N_NODES + NT - 1) / NT)

typedef __attribute__((ext_vector_type(8))) short bf16x8;
typedef __attribute__((ext_vector_type(4))) float f32x4;

__device__ __forceinline__ unsigned short f2bf(float f) {
  unsigned int u = __float_as_uint(f);
  u = (u + 0x7FFFu + ((u >> 16) & 1u)) >> 16;   // RNE
  return (unsigned short)u;
}
__device__ __forceinline__ float bflo(unsigned int u) { return __uint_as_float(u << 16); }
__device__ __forceinline__ float bfhi(unsigned int u) { return __uint_as_float(u & 0xFFFF0000u); }

__device__ __forceinline__ bf16x8 cvt8(float4 u, float4 v) {
  bf16x8 r;
  r[0] = (short)f2bf(u.x); r[1] = (short)f2bf(u.y);
  r[2] = (short)f2bf(u.z); r[3] = (short)f2bf(u.w);
  r[4] = (short)f2bf(v.x); r[5] = (short)f2bf(v.y);
  r[6] = (short)f2bf(v.z); r[7] = (short)f2bf(v.w);
  return r;
}

struct StageRegs { float4 a, b, c, d; };

__device__ __forceinline__ void load_tile(const float* __restrict__ E, int tile,
                                          int srow, int sg, StageRegs& s) {
  int grow = tile * NT + srow;
  if (grow < N_NODES) {
    const float4* p = reinterpret_cast<const float4*>(E + (size_t)grow * HID + sg * 8);
    s.a = p[0]; s.b = p[1]; s.c = p[32]; s.d = p[33];
  } else {
    s.a = s.b = s.c = s.d = make_float4(0.f, 0.f, 0.f, 0.f);
  }
}

// ---- kernel 1: Wcat^T in MFMA-fragment order (coalesced reads).
__global__ __launch_bounds__(128) void pack_w_kernel(
    const float* __restrict__ W1, unsigned short* __restrict__ Wtf) {
  int k = blockIdx.x;          // 0..255
  int t = threadIdx.x;         // 0..127
  int half = t >> 6;
  int jj = (t & 63) * 4;
  const float4 v = *reinterpret_cast<const float4*>(
      W1 + (size_t)(half ? (HID + k) : k) * HID + jj);
  float vv[4] = {v.x, v.y, v.z, v.w};
#pragma unroll
  for (int e = 0; e < 4; ++e) {
    int j = half * HID + jj + e;
    int f    = (j >> 4) * 8 + (k >> 5);
    int lane = (j & 15) | (((k >> 3) & 3) << 4);
    int elem = k & 7;
    Wtf[f * 512 + lane * 8 + elem] = f2bf(vv[e]);
  }
}

// ---- kernel 2: weights-stationary streaming GEMM, depth-2 prefetch.
__global__ __launch_bounds__(512, 2) void gemm_kernel(
    const float* __restrict__ E, const unsigned short* __restrict__ Wtf,
    const float* __restrict__ b1, unsigned short* __restrict__ P) {
  __shared__ alignas(16) char lds0[16384];   // 32 rows x 512B bf16, XOR-swizzled
  __shared__ alignas(16) char lds1[16384];
  const int tid  = threadIdx.x;
  const int lane = tid & 63;
  const int w    = tid >> 6;                 // 0..7

  // persistent A fragments: wave w owns P-cols [w*64, w*64+64) x K=256 (128 VGPR)
  bf16x8 a[4][8];
#pragma unroll
  for (int m = 0; m < 4; ++m)
#pragma unroll
    for (int kk = 0; kk < 8; ++kk)
      a[m][kk] = *reinterpret_cast<const bf16x8*>(
          Wtf + (((size_t)(w * 4 + m) * 8 + kk) << 9) + lane * 8);

  float4 bv[4];
#pragma unroll
  for (int m = 0; m < 4; ++m) {
    int fm = w * 4 + m;
    bv[m] = (fm < 16) ? *reinterpret_cast<const float4*>(b1 + fm * 16 + ((lane >> 4) << 2))
                      : make_float4(0.f, 0.f, 0.f, 0.f);
  }

  const int srow = tid >> 4;               // 0..31
  const int sg   = tid & 15;
  const int woff0 = srow * 512 + ((sg * 16) ^ ((srow & 7) << 4));
  const int woff1 = srow * 512 + (((sg + 16) * 16) ^ ((srow & 7) << 4));
  const int G = gridDim.x;

  auto write_tile = [&](char* buf, const StageRegs& s) {
    *reinterpret_cast<bf16x8*>(&buf[woff0]) = cvt8(s.a, s.b);
    *reinterpret_cast<bf16x8*>(&buf[woff1]) = cvt8(s.c, s.d);
  };

  auto compute_store = [&](const char* buf, int tt) {
    f32x4 acc[4][2] = {};
#pragma unroll
    for (int n = 0; n < 2; ++n) {
      int r   = n * 16 + (lane & 15);
      int rb  = r * 512;
      int sw  = (r & 7) << 4;
      int kb0 = (lane >> 4) << 4;
      bf16x8 bfr[8];
#pragma unroll
      for (int kk = 0; kk < 8; ++kk)
        bfr[kk] = *reinterpret_cast<const bf16x8*>(&buf[rb + ((kk * 64 + kb0) ^ sw)]);
#pragma unroll
      for (int kk = 0; kk < 8; ++kk)
#pragma unroll
        for (int m = 0; m < 4; ++m)
          acc[m][n] = __builtin_amdgcn_mfma_f32_16x16x32_bf16(a[m][kk], bfr[kk], acc[m][n], 0, 0, 0);
    }
#pragma unroll
    for (int m = 0; m < 4; ++m) {
      int pcb = (w * 4 + m) * 16 + ((lane >> 4) << 2);
#pragma unroll
      for (int n = 0; n < 2; ++n) {
        int node = tt * NT + n * 16 + (lane & 15);
        if (node < N_NODES) {
          ushort4 o;
          o.x = f2bf(acc[m][n][0] + bv[m].x);
          o.y = f2bf(acc[m][n][1] + bv[m].y);
          o.z = f2bf(acc[m][n][2] + bv[m].z);
          o.w = f2bf(acc[m][n][3] + bv[m].w);
          *reinterpret_cast<ushort4*>(P + (size_t)node * 512 + pcb) = o;
        }
      }
    }
  };

  int t = blockIdx.x;
  StageRegs sX, sY;
  // prologue: lds0 <- tile t; sY <- t+G; sX <- t+2G (depth-2 in flight)
  load_tile(E, t, srow, sg, sX);
  if (t + G < NTILES) load_tile(E, t + G, srow, sg, sY);
  write_tile(lds0, sX);
  if (t + 2 * G < NTILES) load_tile(E, t + 2 * G, srow, sg, sX);
  __syncthreads();

  while (true) {
    // phase A: lds0 = tile t; sY = t+G; sX = t+2G
    compute_store(lds0, t);
    if (t + G >= NTILES) break;
    write_tile(lds1, sY);
    if (t + 3 * G < NTILES) load_tile(E, t + 3 * G, srow, sg, sY);
    __syncthreads();
    t += G;
    // phase B: lds1 = tile t; sX = t+G; sY = t+2G
    compute_store(lds1, t);
    if (t + G >= NTILES) break;
    write_tile(lds0, sX);
    if (t + 3 * G < NTILES) load_tile(E, t + 3 * G, srow, sg, sX);
    __syncthreads();
    t += G;
  }
}

// ---- kernel 3: 2 edges per 32-lane half per iteration (4 gathers in flight).
__global__ __launch_bounds__(256) void edge_kernel(
    const int* __restrict__ idx, const unsigned short* __restrict__ P,
    const float* __restrict__ W2, const float* __restrict__ b2,
    float* __restrict__ out) {
  const int tid  = threadIdx.x;
  const int lane = tid & 63;
  const int l32  = lane & 31;
  const int half = lane >> 5;
  const int wv     = blockIdx.x * 4 + (tid >> 6);
  const int nwaves = gridDim.x * 4;
  const float4 w0 = *reinterpret_cast<const float4*>(W2 + l32 * 8);
  const float4 w1 = *reinterpret_cast<const float4*>(W2 + l32 * 8 + 4);
  const float bias = b2[0];

  auto dotrelu = [&](uint4 ua, uint4 ub) -> float {
    float h0 = fmaxf(bflo(ua.x) + bflo(ub.x), 0.f);
    float h1 = fmaxf(bfhi(ua.x) + bfhi(ub.x), 0.f);
    float h2 = fmaxf(bflo(ua.y) + bflo(ub.y), 0.f);
    float h3 = fmaxf(bfhi(ua.y) + bfhi(ub.y), 0.f);
    float h4 = fmaxf(bflo(ua.z) + bflo(ub.z), 0.f);
    float h5 = fmaxf(bfhi(ua.z) + bfhi(ub.z), 0.f);
    float h6 = fmaxf(bflo(ua.w) + bflo(ub.w), 0.f);
    float h7 = fmaxf(bfhi(ua.w) + bfhi(ub.w), 0.f);
    return h0 * w0.x + h1 * w0.y + h2 * w0.z + h3 * w0.w
         + h4 * w1.x + h5 * w1.y + h6 * w1.z + h7 * w1.w;
  };

  for (int ep = wv; ep < N_EDGES / 2; ep += 2 * nwaves) {
    int eA  = ep * 2 + half;
    int epB = ep + nwaves;
    bool hasB = (epB < N_EDGES / 2);
    int eB  = hasB ? (epB * 2 + half) : eA;
    int sA = idx[eA];
    int tA = idx[N_EDGES + eA];
    int sB = idx[eB];
    int tB = idx[N_EDGES + eB];
    uint4 uaA = *reinterpret_cast<const uint4*>(P + (size_t)sA * 512 + l32 * 8);
    uint4 ubA = *reinterpret_cast<const uint4*>(P + (size_t)tA * 512 + 256 + l32 * 8);
    uint4 uaB = *reinterpret_cast<const uint4*>(P + (size_t)sB * 512 + l32 * 8);
    uint4 ubB = *reinterpret_cast<const uint4*>(P + (size_t)tB * 512 + 256 + l32 * 8);
    float accA = dotrelu(uaA, ubA);
    float accB = dotrelu(uaB, ubB);
#pragma unroll
    for (int off = 1; off < 32; off <<= 1) {
      accA += __shfl_xor(accA, off, 64);
      accB += __shfl_xor(accB, off, 64);
    }
    if (l32 == 0) {
      out[eA] = accA + bias;
      if (hasB) out[eB] = accB + bias;
    }
  }
}

extern "C" void kernel_launch(void* const* d_in, const int* in_sizes, int n_in,
                              void* d_out, int out_size, void* d_ws, size_t ws_size,
                              hipStream_t stream) {
  const float* E   = (const float*)d_in[0];
  const int*   idx = (const int*)d_in[1];
  const float* W1  = (const float*)d_in[2];
  const float* b1  = (const float*)d_in[3];
  const float* W2  = (const float*)d_in[4];
  const float* b2  = (const float*)d_in[5];
  float* out = (float*)d_out;

  unsigned short* Wtf = (unsigned short*)d_ws;                          // 256 KiB
  unsigned short* P   = (unsigned short*)((char*)d_ws + 512 * HID * 2); // 48.8 MiB

  hipLaunchKernelGGL(pack_w_kernel, dim3(HID), dim3(128), 0, stream, W1, Wtf);
  hipLaunchKernelGGL(gemm_kernel, dim3(256), dim3(512), 0, stream, E, Wtf, b1, P);
  hipLaunchKernelGGL(edge_kernel, dim3(2048), dim3(256), 0, stream, idx, P, W2, b2, out);
}